// Round 3
// baseline (235.646 us; speedup 1.0000x reference)
//
#include <hip/hip_runtime.h>
#include <math.h>

#define HH 512
#define WW 512
#define BB 4
#define NPIX (BB * HH * WW)

#define T_H 8
#define T_W 64
#define GX (WW / T_W)       // 8
#define GY (HH / T_H)       // 64
#define I_ROWS (T_H + 4)    // 12 rows: h0-2 .. h0+T_H+1
#define I_COLS (T_W + 4)    // 68 cols: w0-2 .. w0+T_W+1
#define S_ROWS (T_H + 3)    // 11 rows: h0-1 .. h0+T_H+1
#define S_COLS (T_W + 2)    // 66 cols: w0-1 .. w0+T_W
#define LST 68              // LDS row stride

constexpr float TAUf   = 0.01f;
constexpr float RHOf   = 1.99f;
constexpr float SIGMAf = (float)(1.0 / 0.01 / 72.0);
constexpr float INV_1P_TAU = (float)(1.0 / 1.01);

// epsilon2_adjoint at (h,w), full bounds checks (edge path).
__device__ __forceinline__ void eps2_adj_edge(
    const float* __restrict__ u0, const float* __restrict__ u1,
    const float* __restrict__ u2c, const float* __restrict__ u3,
    int boff, int h, int w, float& i0, float& i1)
{
    int base = boff + h * WW + w;
    float G0  = u0[base];
    float G0d = (h < HH - 1) ? u0[base + WW] : 0.f;
    float G1c = (w >= 1)     ? u1[base]      : 0.f;
    float G1r = (w < WW - 1) ? u1[base + 1]  : 0.f;
    i0 = G0 - G0d - G1r + G1c;
    float G2  = u2c[base];
    float G2r = (w < WW - 1) ? u2c[base + 1] : 0.f;
    float G3  = (h < HH - 1) ? u3[base]      : 0.f;
    float G3u = (h >= 1)     ? u3[base - WW] : 0.f;
    i1 = G2 - G2r - G3 + G3u;
}

template <bool FIRST, bool LAST>
__global__ __launch_bounds__(256) void fused_iter(
    const float* __restrict__ y, const int* __restrict__ ths_p,
    const float* __restrict__ x2_in, float* __restrict__ x2_out,
    const float* __restrict__ r20_in, const float* __restrict__ r21_in,
    float* __restrict__ r20_out, float* __restrict__ r21_out,
    const float* __restrict__ u0_in, const float* __restrict__ u1_in,
    const float* __restrict__ u2_in, const float* __restrict__ u3_in,
    float* __restrict__ u0_out, float* __restrict__ u1_out,
    float* __restrict__ u2_out, float* __restrict__ u3_out)
{
    __shared__ float i0s[I_ROWS][LST], i1s[I_ROWS][LST];
    __shared__ float ss[S_ROWS][LST], t0s[S_ROWS][LST], t1s[S_ROWS][LST];

    const int tid = threadIdx.x;
    const int bx = blockIdx.x, by = blockIdx.y;
    const int w0 = bx * T_W, h0 = by * T_H;
    const int boff = blockIdx.z * (HH * WW);
    // interior blocks: every access in all phases is in-image -> no bounds checks
    const bool interior = (bx > 0) && (bx < GX - 1) && (by > 0) && (by < GY - 1);

    const float ths = (float)ths_p[0];
    const float inv_taulam1 = 1.0f / (TAUf * (ths * 0.1f));
    const float inv_lam2 = 1.0f / (ths * 0.15f);

    // ---- phase 0: i = eps2_adj(u_in) over I_ROWS x I_COLS -> LDS ----
    if (!FIRST) {
        if (interior) {
            for (int p = tid; p < I_ROWS * I_COLS; p += 256) {
                int ih = p / I_COLS, iw = p - ih * I_COLS;
                int base = boff + (h0 - 2 + ih) * WW + (w0 - 2 + iw);
                float i0 = u0_in[base] - u0_in[base + WW]
                         - u1_in[base + 1] + u1_in[base];
                float i1 = u2_in[base] - u2_in[base + 1]
                         - u3_in[base] + u3_in[base - WW];
                i0s[ih][iw] = i0;
                i1s[ih][iw] = i1;
            }
        } else {
            for (int p = tid; p < I_ROWS * I_COLS; p += 256) {
                int ih = p / I_COLS, iw = p - ih * I_COLS;
                int h = h0 - 2 + ih, w = w0 - 2 + iw;
                float i0 = 0.f, i1 = 0.f;
                if (h >= 0 && h < HH && w >= 0 && w < WW)
                    eps2_adj_edge(u0_in, u1_in, u2_in, u3_in, boff, h, w, i0, i1);
                i0s[ih][iw] = i0;
                i1s[ih][iw] = i1;
            }
        }
        __syncthreads();
    }

    // ---- phase 1 ----
    if (FIRST) {
        // analytic iter 0: x = y, r = 0  =>  s = y, t = 0, x2_out = y, r2_out = 0
        for (int p = tid; p < S_ROWS * S_COLS; p += 256) {
            int sh = p / S_COLS, sw = p - sh * S_COLS;
            int h = h0 - 1 + sh, w = w0 - 1 + sw;
            float sv = 0.f;
            if (h >= 0 && h < HH && w >= 0 && w < WW) {
                int idx = boff + h * WW + w;
                float yv = y[idx];
                sv = yv;
                if (sh >= 1 && sh <= T_H && sw >= 1 && sw <= T_W) {
                    x2_out[idx] = yv;
                    r20_out[idx] = 0.f;
                    r21_out[idx] = 0.f;
                }
            }
            ss[sh][sw] = sv;
            t0s[sh][sw] = 0.f;
            t1s[sh][sw] = 0.f;
        }
        __syncthreads();
    } else if (LAST) {
        // only x needed, interior 8x64, no LDS round-trip
        #pragma unroll
        for (int k = 0; k < 2; ++k) {
            int lh = (tid >> 6) * 2 + k;
            int lw = tid & 63;
            int h = h0 + lh, w = w0 + lw;
            int idx = boff + h * WW + w;
            int sh = lh + 1, sw = lw + 1;
            float i0c = i0s[sh + 1][sw + 1], i0l = i0s[sh + 1][sw];
            float i1c = i1s[sh + 1][sw + 1], i1u = i1s[sh][sw + 1];
            float na;
            if (interior) {
                na = TAUf * (i0l - i0c + i1u - i1c);
            } else {
                na = 0.f;
                if (w < WW - 1) na -= TAUf * i0c;
                if (w >= 1)     na += TAUf * i0l;
                if (h < HH - 1) na -= TAUf * i1c;
                if (h >= 1)     na += TAUf * i1u;
            }
            float yv  = y[idx];
            float x2v = x2_in[idx];
            float x = (x2v - na + TAUf * yv) * INV_1P_TAU;
            x2_out[idx] = x2v + RHOf * (x - x2v);
        }
        return;
    } else {
        if (interior) {
            for (int p = tid; p < S_ROWS * S_COLS; p += 256) {
                int sh = p / S_COLS, sw = p - sh * S_COLS;
                int h = h0 - 1 + sh, w = w0 - 1 + sw;
                int idx = boff + h * WW + w;
                float i0c = i0s[sh + 1][sw + 1], i0l = i0s[sh + 1][sw];
                float i1c = i1s[sh + 1][sw + 1], i1u = i1s[sh][sw + 1];
                float na = TAUf * (i0l - i0c + i1u - i1c);
                float yv  = y[idx];
                float x2v = x2_in[idx];
                float x = (x2v - na + TAUf * yv) * INV_1P_TAU;
                float r20v = r20_in[idx], r21v = r21_in[idx];
                float rr0 = r20v + TAUf * i0c;
                float rr1 = r21v + TAUf * i1c;
                float mag = sqrtf(rr0 * rr0 + rr1 * rr1) * inv_taulam1;
                float rinv = 1.0f / fmaxf(mag, 1.0f);
                float r0 = rr0 - rr0 * rinv;
                float r1 = rr1 - rr1 * rinv;
                ss[sh][sw]  = 2.0f * x  - x2v;
                t0s[sh][sw] = 2.0f * r0 - r20v;
                t1s[sh][sw] = 2.0f * r1 - r21v;
                if (sh >= 1 && sh <= T_H && sw >= 1 && sw <= T_W) {
                    x2_out[idx]  = x2v + RHOf * (x - x2v);
                    r20_out[idx] = r20v + RHOf * (r0 - r20v);
                    r21_out[idx] = r21v + RHOf * (r1 - r21v);
                }
            }
        } else {
            for (int p = tid; p < S_ROWS * S_COLS; p += 256) {
                int sh = p / S_COLS, sw = p - sh * S_COLS;
                int h = h0 - 1 + sh, w = w0 - 1 + sw;
                float sv = 0.f, t0v = 0.f, t1v = 0.f;
                if (h >= 0 && h < HH && w >= 0 && w < WW) {
                    int idx = boff + h * WW + w;
                    float i0c = i0s[sh + 1][sw + 1], i0l = i0s[sh + 1][sw];
                    float i1c = i1s[sh + 1][sw + 1], i1u = i1s[sh][sw + 1];
                    float na = 0.f;
                    if (w < WW - 1) na -= TAUf * i0c;
                    if (w >= 1)     na += TAUf * i0l;
                    if (h < HH - 1) na -= TAUf * i1c;
                    if (h >= 1)     na += TAUf * i1u;
                    float yv  = y[idx];
                    float x2v = x2_in[idx];
                    float x = (x2v - na + TAUf * yv) * INV_1P_TAU;
                    float r20v = r20_in[idx], r21v = r21_in[idx];
                    float rr0 = r20v + TAUf * i0c;
                    float rr1 = r21v + TAUf * i1c;
                    float mag = sqrtf(rr0 * rr0 + rr1 * rr1) * inv_taulam1;
                    float rinv = 1.0f / fmaxf(mag, 1.0f);
                    float r0 = rr0 - rr0 * rinv;
                    float r1 = rr1 - rr1 * rinv;
                    sv  = 2.0f * x  - x2v;
                    t0v = 2.0f * r0 - r20v;
                    t1v = 2.0f * r1 - r21v;
                    if (sh >= 1 && sh <= T_H && sw >= 1 && sw <= T_W) {
                        x2_out[idx]  = x2v + RHOf * (x - x2v);
                        r20_out[idx] = r20v + RHOf * (r0 - r20v);
                        r21_out[idx] = r21v + RHOf * (r1 - r21v);
                    }
                }
                ss[sh][sw]  = sv;
                t0s[sh][sw] = t0v;
                t1s[sh][sw] = t1v;
            }
        }
        __syncthreads();
    }

    // ---- phase 2: dual update on 8x64 interior ----
    #pragma unroll
    for (int k = 0; k < 2; ++k) {
        int lh = (tid >> 6) * 2 + k;
        int lw = tid & 63;
        int h = h0 + lh, w = w0 + lw;
        int idx = boff + h * WW + w;
        int sh = lh + 1, sw = lw + 1;

        float G0, G1, G2, G3;
        if (interior) {
            float scc = ss[sh][sw];
            float scl = ss[sh][sw - 1];
            float sdn = ss[sh + 1][sw];
            float v0c = ss[sh][sw + 1] - scc - t0s[sh][sw];
            float v1c = sdn - scc - t1s[sh][sw];
            float v0u = ss[sh - 1][sw + 1] - ss[sh - 1][sw] - t0s[sh - 1][sw];
            float v0l = scc - scl - t0s[sh][sw - 1];
            float v1l = ss[sh + 1][sw - 1] - scl - t1s[sh][sw - 1];
            float v1d = ss[sh + 2][sw] - sdn - t1s[sh + 1][sw];
            G0 = v0c - v0u;
            G1 = v0c - v0l;
            G2 = v1c - v1l;
            G3 = v1d - v1c;
        } else {
            auto v0f = [&](int sh2, int sw2, int w2) -> float {
                float d = (w2 < WW - 1) ? (ss[sh2][sw2 + 1] - ss[sh2][sw2]) : 0.f;
                return d - t0s[sh2][sw2];
            };
            auto v1f = [&](int sh2, int sw2, int h2) -> float {
                float d = (h2 < HH - 1) ? (ss[sh2 + 1][sw2] - ss[sh2][sw2]) : 0.f;
                return d - t1s[sh2][sw2];
            };
            float v0c = v0f(sh, sw, w);
            float v1c = v1f(sh, sw, h);
            G0 = v0c - ((h >= 1) ? v0f(sh - 1, sw, w) : 0.f);
            G1 = (w >= 1) ? (v0c - v0f(sh, sw - 1, w - 1)) : 0.f;
            G2 = v1c - ((w >= 1) ? v1f(sh, sw - 1, h) : 0.f);
            G3 = (h < HH - 1) ? (v1f(sh + 1, sw, h + 1) - v1c) : 0.f;
        }

        float u0v, u1v, u2v, u3v;
        if (FIRST) {
            u0v = 0.f; u1v = 0.f; u2v = 0.f; u3v = 0.f;
        } else {
            u0v = u0_in[idx]; u1v = u1_in[idx];
            u2v = u2_in[idx]; u3v = u3_in[idx];
        }
        float uu0 = u0v + SIGMAf * G0;
        float uu1 = u1v + SIGMAf * G1;
        float uu2 = u2v + SIGMAf * G2;
        float uu3 = u3v + SIGMAf * G3;

        float mag = sqrtf(uu0 * uu0 + uu1 * uu1 + uu2 * uu2 + uu3 * uu3) * inv_lam2;
        float uinv = 1.0f / fmaxf(mag, 1.0f);
        float n0 = uu0 * uinv, n1 = uu1 * uinv, n2 = uu2 * uinv, n3 = uu3 * uinv;

        u0_out[idx] = u0v + RHOf * (n0 - u0v);
        u1_out[idx] = u1v + RHOf * (n1 - u1v);
        u2_out[idx] = u2v + RHOf * (n2 - u2v);
        u3_out[idx] = u3v + RHOf * (n3 - u3v);
    }
}

extern "C" void kernel_launch(void* const* d_in, const int* in_sizes, int n_in,
                              void* d_out, int out_size, void* d_ws, size_t ws_size,
                              hipStream_t stream)
{
    const float* y   = (const float*)d_in[0];
    const int*   ths = (const int*)d_in[1];
    float* ws = (float*)d_ws;

    // 7 state planes x 2 (ping-pong): x2, r20, r21, u0, u1, u2, u3
    float* A[7];
    float* B[7];
    for (int i = 0; i < 7; ++i) {
        A[i] = ws + (size_t)i * NPIX;
        B[i] = ws + (size_t)(7 + i) * NPIX;
    }

    float** in  = A;   // iter 0 ignores `in` (FIRST)
    float** out = B;

    dim3 block(256);
    dim3 grid(GX, GY, BB);

    for (int it = 0; it < 10; ++it) {
        float* xout = (it == 9) ? (float*)d_out : out[0];
        if (it == 0) {
            fused_iter<true, false><<<grid, block, 0, stream>>>(
                y, ths, in[0], xout, in[1], in[2], out[1], out[2],
                in[3], in[4], in[5], in[6], out[3], out[4], out[5], out[6]);
        } else if (it == 9) {
            fused_iter<false, true><<<grid, block, 0, stream>>>(
                y, ths, in[0], xout, in[1], in[2], out[1], out[2],
                in[3], in[4], in[5], in[6], out[3], out[4], out[5], out[6]);
        } else {
            fused_iter<false, false><<<grid, block, 0, stream>>>(
                y, ths, in[0], xout, in[1], in[2], out[1], out[2],
                in[3], in[4], in[5], in[6], out[3], out[4], out[5], out[6]);
        }
        float** t = in; in = out; out = t;
    }
}

// Round 4
// 202.755 us; speedup vs baseline: 1.1622x; 1.1622x over previous
//
#include <hip/hip_runtime.h>
#include <hip/hip_fp16.h>
#include <math.h>

#define HH 512
#define WW 512
#define BB 4
#define NPIX (BB * HH * WW)

#define T_H 16
#define T_W 64
#define GX (WW / T_W)       // 8
#define GY (HH / T_H)       // 32
#define I_ROWS (T_H + 4)    // 20 rows: h0-2 .. h0+T_H+1
#define I_COLS (T_W + 4)    // 68 cols: w0-2 .. w0+T_W+1
#define S_ROWS (T_H + 3)    // 19 rows: h0-1 .. h0+T_H+1
#define S_COLS (T_W + 2)    // 66 cols: w0-1 .. w0+T_W
#define LST 68              // LDS row stride (f32)

constexpr float TAUf   = 0.01f;
constexpr float RHOf   = 1.99f;
constexpr float SIGMAf = (float)(1.0 / 0.01 / 72.0);
constexpr float INV_1P_TAU = (float)(1.0 / 1.01);

struct h4 { __half x, y, z, w; };

__device__ __forceinline__ h4 ldu4(const __half* __restrict__ u, int idx) {
    return *(const h4*)(u + 4 * (size_t)idx);
}

template <bool FIRST, bool LAST>
__global__ __launch_bounds__(256) void fused_iter(
    const float* __restrict__ y, const int* __restrict__ ths_p,
    const __half* __restrict__ x2_in, __half* __restrict__ x2_out_h,
    float* __restrict__ x2_out_f,
    const __half* __restrict__ r2_in, __half* __restrict__ r2_out,
    const __half* __restrict__ u_in, __half* __restrict__ u_out)
{
    __shared__ float i0s[I_ROWS][LST], i1s[I_ROWS][LST];
    __shared__ float ss[S_ROWS][LST], t0s[S_ROWS][LST], t1s[S_ROWS][LST];

    const int tid = threadIdx.x;
    const int bx = blockIdx.x, by = blockIdx.y;
    const int w0 = bx * T_W, h0 = by * T_H;
    const int boff = blockIdx.z * (HH * WW);
    const bool interior = (bx > 0) && (bx < GX - 1) && (by > 0) && (by < GY - 1);

    const float ths = (float)ths_p[0];
    const float inv_taulam1 = 1.0f / (TAUf * (ths * 0.1f));
    const float inv_lam2 = 1.0f / (ths * 0.15f);

    // ---- phase 0: i = eps2_adj(u_in) over I_ROWS x I_COLS -> LDS ----
    if (!FIRST) {
        if (interior) {
            for (int p = tid; p < I_ROWS * I_COLS; p += 256) {
                int ih = p / I_COLS, iw = p - ih * I_COLS;
                int idx = boff + (h0 - 2 + ih) * WW + (w0 - 2 + iw);
                h4 uc = ldu4(u_in, idx);
                h4 ud = ldu4(u_in, idx + WW);
                h4 ur = ldu4(u_in, idx + 1);
                h4 uu = ldu4(u_in, idx - WW);
                i0s[ih][iw] = __half2float(uc.x) - __half2float(ud.x)
                            - __half2float(ur.y) + __half2float(uc.y);
                i1s[ih][iw] = __half2float(uc.z) - __half2float(ur.z)
                            - __half2float(uc.w) + __half2float(uu.w);
            }
        } else {
            for (int p = tid; p < I_ROWS * I_COLS; p += 256) {
                int ih = p / I_COLS, iw = p - ih * I_COLS;
                int h = h0 - 2 + ih, w = w0 - 2 + iw;
                float i0 = 0.f, i1 = 0.f;
                if (h >= 0 && h < HH && w >= 0 && w < WW) {
                    int idx = boff + h * WW + w;
                    h4 uc = ldu4(u_in, idx);
                    float u0c = __half2float(uc.x), u1c = __half2float(uc.y);
                    float u2c = __half2float(uc.z), u3c = __half2float(uc.w);
                    float u0d = 0.f, u1r = 0.f, u2r = 0.f, u3u = 0.f;
                    if (h < HH - 1) u0d = __half2float(ldu4(u_in, idx + WW).x);
                    if (w < WW - 1) { h4 ur = ldu4(u_in, idx + 1);
                                      u1r = __half2float(ur.y); u2r = __half2float(ur.z); }
                    if (h >= 1)     u3u = __half2float(ldu4(u_in, idx - WW).w);
                    i0 = u0c - u0d - u1r + ((w >= 1) ? u1c : 0.f);
                    i1 = u2c - u2r - ((h < HH - 1) ? u3c : 0.f) + u3u;
                }
                i0s[ih][iw] = i0;
                i1s[ih][iw] = i1;
            }
        }
        __syncthreads();
    }

    // ---- phase 1 ----
    if (FIRST) {
        // analytic iter 0: x = y, r = 0 => s = y, t = 0, x2_out = y, r2_out = 0
        for (int p = tid; p < S_ROWS * S_COLS; p += 256) {
            int sh = p / S_COLS, sw = p - sh * S_COLS;
            int h = h0 - 1 + sh, w = w0 - 1 + sw;
            float sv = 0.f;
            if (h >= 0 && h < HH && w >= 0 && w < WW) {
                int idx = boff + h * WW + w;
                float yv = y[idx];
                sv = yv;
                if (sh >= 1 && sh <= T_H && sw >= 1 && sw <= T_W) {
                    x2_out_h[idx] = __float2half(yv);
                    *(__half2*)(r2_out + 2 * (size_t)idx) =
                        __halves2half2(__float2half(0.f), __float2half(0.f));
                }
            }
            ss[sh][sw]  = sv;
            t0s[sh][sw] = 0.f;
            t1s[sh][sw] = 0.f;
        }
        __syncthreads();
    } else if (LAST) {
        // only x needed, interior 16x64, write f32 output
        #pragma unroll
        for (int k = 0; k < 4; ++k) {
            int lh = (tid >> 6) + (k << 2);
            int lw = tid & 63;
            int h = h0 + lh, w = w0 + lw;
            int idx = boff + h * WW + w;
            int sh = lh + 1, sw = lw + 1;
            float i0c = i0s[sh + 1][sw + 1], i0l = i0s[sh + 1][sw];
            float i1c = i1s[sh + 1][sw + 1], i1u = i1s[sh][sw + 1];
            float na;
            if (interior) {
                na = TAUf * (i0l - i0c + i1u - i1c);
            } else {
                na = 0.f;
                if (w < WW - 1) na -= TAUf * i0c;
                if (w >= 1)     na += TAUf * i0l;
                if (h < HH - 1) na -= TAUf * i1c;
                if (h >= 1)     na += TAUf * i1u;
            }
            float yv  = y[idx];
            float x2v = __half2float(x2_in[idx]);
            float x = (x2v - na + TAUf * yv) * INV_1P_TAU;
            x2_out_f[idx] = x2v + RHOf * (x - x2v);
        }
        return;
    } else {
        for (int p = tid; p < S_ROWS * S_COLS; p += 256) {
            int sh = p / S_COLS, sw = p - sh * S_COLS;
            int h = h0 - 1 + sh, w = w0 - 1 + sw;
            float sv = 0.f, t0v = 0.f, t1v = 0.f;
            bool in_img = interior || (h >= 0 && h < HH && w >= 0 && w < WW);
            if (in_img) {
                int idx = boff + h * WW + w;
                float i0c = i0s[sh + 1][sw + 1], i0l = i0s[sh + 1][sw];
                float i1c = i1s[sh + 1][sw + 1], i1u = i1s[sh][sw + 1];
                float na;
                if (interior) {
                    na = TAUf * (i0l - i0c + i1u - i1c);
                } else {
                    na = 0.f;
                    if (w < WW - 1) na -= TAUf * i0c;
                    if (w >= 1)     na += TAUf * i0l;
                    if (h < HH - 1) na -= TAUf * i1c;
                    if (h >= 1)     na += TAUf * i1u;
                }
                float yv  = y[idx];
                float x2v = __half2float(x2_in[idx]);
                float x = (x2v - na + TAUf * yv) * INV_1P_TAU;
                __half2 r2v2 = *(const __half2*)(r2_in + 2 * (size_t)idx);
                float r20v = __half2float(r2v2.x);
                float r21v = __half2float(r2v2.y);
                float rr0 = r20v + TAUf * i0c;
                float rr1 = r21v + TAUf * i1c;
                float mag = sqrtf(rr0 * rr0 + rr1 * rr1) * inv_taulam1;
                float rinv = 1.0f / fmaxf(mag, 1.0f);
                float r0 = rr0 - rr0 * rinv;
                float r1 = rr1 - rr1 * rinv;
                sv  = 2.0f * x  - x2v;
                t0v = 2.0f * r0 - r20v;
                t1v = 2.0f * r1 - r21v;
                if (sh >= 1 && sh <= T_H && sw >= 1 && sw <= T_W) {
                    x2_out_h[idx] = __float2half(x2v + RHOf * (x - x2v));
                    *(__half2*)(r2_out + 2 * (size_t)idx) = __halves2half2(
                        __float2half(r20v + RHOf * (r0 - r20v)),
                        __float2half(r21v + RHOf * (r1 - r21v)));
                }
            }
            ss[sh][sw]  = sv;
            t0s[sh][sw] = t0v;
            t1s[sh][sw] = t1v;
        }
        __syncthreads();
    }

    // ---- phase 2: dual update on 16x64 interior ----
    #pragma unroll
    for (int k = 0; k < 4; ++k) {
        int lh = (tid >> 6) + (k << 2);
        int lw = tid & 63;
        int h = h0 + lh, w = w0 + lw;
        int idx = boff + h * WW + w;
        int sh = lh + 1, sw = lw + 1;

        float G0, G1, G2, G3;
        if (interior) {
            float scc = ss[sh][sw];
            float scl = ss[sh][sw - 1];
            float sdn = ss[sh + 1][sw];
            float v0c = ss[sh][sw + 1] - scc - t0s[sh][sw];
            float v1c = sdn - scc - t1s[sh][sw];
            float v0u = ss[sh - 1][sw + 1] - ss[sh - 1][sw] - t0s[sh - 1][sw];
            float v0l = scc - scl - t0s[sh][sw - 1];
            float v1l = ss[sh + 1][sw - 1] - scl - t1s[sh][sw - 1];
            float v1d = ss[sh + 2][sw] - sdn - t1s[sh + 1][sw];
            G0 = v0c - v0u;
            G1 = v0c - v0l;
            G2 = v1c - v1l;
            G3 = v1d - v1c;
        } else {
            auto v0f = [&](int sh2, int sw2, int w2) -> float {
                float d = (w2 < WW - 1) ? (ss[sh2][sw2 + 1] - ss[sh2][sw2]) : 0.f;
                return d - t0s[sh2][sw2];
            };
            auto v1f = [&](int sh2, int sw2, int h2) -> float {
                float d = (h2 < HH - 1) ? (ss[sh2 + 1][sw2] - ss[sh2][sw2]) : 0.f;
                return d - t1s[sh2][sw2];
            };
            float v0c = v0f(sh, sw, w);
            float v1c = v1f(sh, sw, h);
            G0 = v0c - ((h >= 1) ? v0f(sh - 1, sw, w) : 0.f);
            G1 = (w >= 1) ? (v0c - v0f(sh, sw - 1, w - 1)) : 0.f;
            G2 = v1c - ((w >= 1) ? v1f(sh, sw - 1, h) : 0.f);
            G3 = (h < HH - 1) ? (v1f(sh + 1, sw, h + 1) - v1c) : 0.f;
        }

        float u0v, u1v, u2v, u3v;
        if (FIRST) {
            u0v = 0.f; u1v = 0.f; u2v = 0.f; u3v = 0.f;
        } else {
            h4 uc = ldu4(u_in, idx);
            u0v = __half2float(uc.x); u1v = __half2float(uc.y);
            u2v = __half2float(uc.z); u3v = __half2float(uc.w);
        }
        float uu0 = u0v + SIGMAf * G0;
        float uu1 = u1v + SIGMAf * G1;
        float uu2 = u2v + SIGMAf * G2;
        float uu3 = u3v + SIGMAf * G3;

        float mag = sqrtf(uu0 * uu0 + uu1 * uu1 + uu2 * uu2 + uu3 * uu3) * inv_lam2;
        float uinv = 1.0f / fmaxf(mag, 1.0f);

        h4 un;
        un.x = __float2half(u0v + RHOf * (uu0 * uinv - u0v));
        un.y = __float2half(u1v + RHOf * (uu1 * uinv - u1v));
        un.z = __float2half(u2v + RHOf * (uu2 * uinv - u2v));
        un.w = __float2half(u3v + RHOf * (uu3 * uinv - u3v));
        *(h4*)(u_out + 4 * (size_t)idx) = un;
    }
}

extern "C" void kernel_launch(void* const* d_in, const int* in_sizes, int n_in,
                              void* d_out, int out_size, void* d_ws, size_t ws_size,
                              hipStream_t stream)
{
    const float* y   = (const float*)d_in[0];
    const int*   ths = (const int*)d_in[1];
    __half* ws = (__half*)d_ws;

    // fp16 state, ping-pong: x2 (NPIX), r2 interleaved (2*NPIX), u interleaved (4*NPIX)
    __half* Ax2 = ws;
    __half* Ar2 = ws + (size_t)NPIX;
    __half* Au  = ws + (size_t)3 * NPIX;
    __half* Bx2 = ws + (size_t)7 * NPIX;
    __half* Br2 = ws + (size_t)8 * NPIX;
    __half* Bu  = ws + (size_t)10 * NPIX;

    __half *ix2 = Ax2, *ir2 = Ar2, *iu = Au;
    __half *ox2 = Bx2, *or2 = Br2, *ou = Bu;

    dim3 block(256);
    dim3 grid(GX, GY, BB);

    for (int it = 0; it < 10; ++it) {
        if (it == 0) {
            fused_iter<true, false><<<grid, block, 0, stream>>>(
                y, ths, ix2, ox2, nullptr, ir2, or2, iu, ou);
        } else if (it == 9) {
            fused_iter<false, true><<<grid, block, 0, stream>>>(
                y, ths, ix2, nullptr, (float*)d_out, ir2, or2, iu, ou);
        } else {
            fused_iter<false, false><<<grid, block, 0, stream>>>(
                y, ths, ix2, ox2, nullptr, ir2, or2, iu, ou);
        }
        __half* t;
        t = ix2; ix2 = ox2; ox2 = t;
        t = ir2; ir2 = or2; or2 = t;
        t = iu;  iu  = ou;  ou  = t;
    }
}